// Round 1
// baseline (451.027 us; speedup 1.0000x reference)
//
#include <hip/hip_runtime.h>
#include <hip/hip_bf16.h>
#include <float.h>

#define MAX_L 16

__global__ __launch_bounds__(256) void rejection_sample_kernel(
    const float* __restrict__ draft_probs,   // [NT, V]
    const float* __restrict__ target_probs,  // [NT, V]
    const float* __restrict__ uniform_probs, // [NT]
    const int*   __restrict__ draft_ids,     // [NT]
    const int*   __restrict__ cu,            // [B]
    const int*   __restrict__ bonus,         // [B]
    int*         __restrict__ out,           // [B, L+1]
    int B, int V, int NT, int L)
{
    const int b   = blockIdx.x;
    const int tid = threadIdx.x;

    __shared__ float s_tp[MAX_L], s_dp[MAX_L], s_u[MAX_L];
    __shared__ int   s_did[MAX_L];
    __shared__ int   s_rejected;
    __shared__ int   s_recrow;
    __shared__ int   s_writecol;

    const int start = (b == 0) ? 0 : cu[b - 1];
    const int nd    = cu[b] - start;
    const int nchain = (nd < L) ? nd : L;

    // Parallel gather of chain inputs: 2 dependent load rounds total.
    if (tid < nchain) {
        const int t   = start + tid;
        const int did = draft_ids[t];
        s_did[tid] = did;
        s_u[tid]   = uniform_probs[t];
        const size_t off = (size_t)t * (size_t)V + (size_t)did;
        s_tp[tid] = target_probs[off];
        s_dp[tid] = draft_probs[off];
    }
    __syncthreads();

    if (tid == 0) {
        float pi = 1.0f, U = 1.0f;
        int last = -1;
        for (int i = 0; i < nchain; ++i) {
            const float dpv = s_dp[i];
            const bool  ok  = dpv > 0.0f;
            const float r   = ok ? (s_tp[i] / dpv) : 1.0f;   // IEEE div, matches np
            pi = fminf(pi * r, 1.0f);
            U  = U * s_u[i];
            if (ok && pi >= U) last = i;
        }
        const bool rejected = (nd > 0) && (last != nd - 1);
        int recrow = start + last + 1;
        recrow = recrow < 0 ? 0 : (recrow > NT - 1 ? NT - 1 : recrow);

        int* row = out + (size_t)b * (L + 1);
        for (int i = 0; i <= L; ++i) {
            row[i] = (i <= last) ? s_did[i] : -1;
        }
        if (!rejected) {
            row[nd] = bonus[b];
        }
        s_rejected = rejected ? 1 : 0;
        s_recrow   = recrow;
        s_writecol = last + 1;
    }
    __syncthreads();

    if (!s_rejected) return;

    // Block-wide argmax over target_probs[recrow, :], first-index tie-break.
    const float4* rowp = (const float4*)(target_probs + (size_t)s_recrow * (size_t)V);
    const int n4 = V >> 2;           // V=128000 -> 32000, divisible by 4
    float bestv = -FLT_MAX;
    int   besti = 0x7fffffff;
    for (int j = tid; j < n4; j += blockDim.x) {
        const float4 v = rowp[j];
        const int base = j << 2;
        // ascending index order + strictly-greater => first occurrence kept
        if (v.x > bestv) { bestv = v.x; besti = base;     }
        if (v.y > bestv) { bestv = v.y; besti = base + 1; }
        if (v.z > bestv) { bestv = v.z; besti = base + 2; }
        if (v.w > bestv) { bestv = v.w; besti = base + 3; }
    }
    // scalar tail (V not divisible by 4) — not hit for V=128000 but be general
    for (int j = (n4 << 2) + tid; j < V; j += blockDim.x) {
        const float v = target_probs[(size_t)s_recrow * (size_t)V + j];
        if (v > bestv) { bestv = v; besti = j; }
    }

    __shared__ float sv[256];
    __shared__ int   si[256];
    sv[tid] = bestv;
    si[tid] = besti;
    __syncthreads();
    for (int s = blockDim.x >> 1; s > 0; s >>= 1) {
        if (tid < s) {
            const float ov = sv[tid + s];
            const int   oi = si[tid + s];
            if (ov > sv[tid] || (ov == sv[tid] && oi < si[tid])) {
                sv[tid] = ov;
                si[tid] = oi;
            }
        }
        __syncthreads();
    }
    if (tid == 0) {
        out[(size_t)b * (L + 1) + s_writecol] = si[0];
    }
}

extern "C" void kernel_launch(void* const* d_in, const int* in_sizes, int n_in,
                              void* d_out, int out_size, void* d_ws, size_t ws_size,
                              hipStream_t stream) {
    const float* draft_probs   = (const float*)d_in[0];
    const float* target_probs  = (const float*)d_in[1];
    const float* uniform_probs = (const float*)d_in[2];
    const int*   draft_ids     = (const int*)d_in[3];
    const int*   cu            = (const int*)d_in[4];
    const int*   bonus         = (const int*)d_in[5];
    int*         out           = (int*)d_out;

    const int NT = in_sizes[2];            // uniform_probs is [NT]
    const int V  = in_sizes[0] / NT;       // draft_probs is [NT, V]
    const int B  = in_sizes[4];            // cu_num_draft_tokens is [B]
    const int L  = out_size / B - 1;       // out is [B, L+1]

    rejection_sample_kernel<<<B, 256, 0, stream>>>(
        draft_probs, target_probs, uniform_probs, draft_ids, cu, bonus,
        out, B, V, NT, L);
}

// Round 2
// 408.423 us; speedup vs baseline: 1.1043x; 1.1043x over previous
//
#include <hip/hip_runtime.h>
#include <hip/hip_bf16.h>
#include <float.h>

#define SPLITS 16

// ws layout:
//   [0 .. B*8)            : unsigned long long packed[B]   (atomic argmax slots)
//   [B*8 .. B*8+B*4)      : int flag[B]      (1 = rejected, needs argmax)
//   [.. +B*4)             : int recrow[B]
//   [.. +B*4)             : int writecol[B]

__global__ void chain_kernel(
    const float* __restrict__ draft_probs,
    const float* __restrict__ target_probs,
    const float* __restrict__ uniform_probs,
    const int*   __restrict__ draft_ids,
    const int*   __restrict__ cu,
    const int*   __restrict__ bonus,
    int*         __restrict__ out,
    unsigned long long* __restrict__ packed,
    int* __restrict__ flag, int* __restrict__ recrow, int* __restrict__ writecol,
    int B, int V, int NT, int L)
{
    const int b = blockIdx.x * blockDim.x + threadIdx.x;
    if (b >= B) return;

    const int start = (b == 0) ? 0 : cu[b - 1];
    const int nd    = cu[b] - start;
    const int nchain = (nd < L) ? nd : L;

    float pi = 1.0f, U = 1.0f;
    int last = -1;
    int* row = out + (size_t)b * (L + 1);

    for (int i = 0; i < nchain; ++i) {
        const int t   = start + i;
        const int did = draft_ids[t];
        row[i] = did;                       // provisional; masked below
        const size_t off = (size_t)t * (size_t)V + (size_t)did;
        const float tp = target_probs[off];
        const float dp = draft_probs[off];
        const float uu = uniform_probs[t];
        const bool ok = dp > 0.0f;
        const float r = ok ? (tp / dp) : 1.0f;   // IEEE div, matches np
        pi = fminf(pi * r, 1.0f);
        U  = U * uu;
        if (ok && pi >= U) last = i;
    }
    // mask out non-accepted positions
    for (int i = last + 1; i <= L; ++i) row[i] = -1;

    const bool rejected = (nd > 0) && (last != nd - 1);
    if (!rejected) {
        row[nd] = bonus[b];
    }
    int rr = start + last + 1;
    rr = rr < 0 ? 0 : (rr > NT - 1 ? NT - 1 : rr);

    flag[b]     = rejected ? 1 : 0;
    recrow[b]   = rr;
    writecol[b] = last + 1;
    packed[b]   = 0ull;   // init atomic slot (probs > 0 beat this)
}

__global__ __launch_bounds__(256) void argmax_partial_kernel(
    const float* __restrict__ target_probs,
    const unsigned long long* __restrict__ /*unused*/,
    unsigned long long* __restrict__ packed,
    const int* __restrict__ flag, const int* __restrict__ recrow,
    int V)
{
    const int b = blockIdx.x;
    const int s = blockIdx.y;
    if (!flag[b]) return;

    const int tid = threadIdx.x;
    const float* rowbase = target_probs + (size_t)recrow[b] * (size_t)V;
    const int n4 = V >> 2;
    const int chunk4 = (n4 + SPLITS - 1) / SPLITS;
    const int lo4 = s * chunk4;
    const int hi4 = (lo4 + chunk4 < n4) ? lo4 + chunk4 : n4;

    float bestv = -FLT_MAX;
    int   besti = 0x7fffffff;
    const float4* rowp = (const float4*)rowbase;
    for (int j = lo4 + tid; j < hi4; j += 256) {
        const float4 v = rowp[j];
        const int base = j << 2;
        if (v.x > bestv) { bestv = v.x; besti = base;     }
        if (v.y > bestv) { bestv = v.y; besti = base + 1; }
        if (v.z > bestv) { bestv = v.z; besti = base + 2; }
        if (v.w > bestv) { bestv = v.w; besti = base + 3; }
    }
    if (s == SPLITS - 1) {
        for (int j = (n4 << 2) + tid; j < V; j += 256) {
            const float v = rowbase[j];
            if (v > bestv) { bestv = v; besti = j; }
        }
    }

    __shared__ float sv[256];
    __shared__ int   si[256];
    sv[tid] = bestv;
    si[tid] = besti;
    __syncthreads();
    for (int w = 128; w > 0; w >>= 1) {
        if (tid < w) {
            const float ov = sv[tid + w];
            const int   oi = si[tid + w];
            if (ov > sv[tid] || (ov == sv[tid] && oi < si[tid])) {
                sv[tid] = ov;
                si[tid] = oi;
            }
        }
        __syncthreads();
    }
    if (tid == 0 && sv[0] > -FLT_MAX) {
        // pack: high 32 = float bits (nonneg => order-monotone),
        // low 32 = ~index => among equal values, larger ~index = smaller index
        const unsigned int fbits = __float_as_uint(sv[0]);
        const unsigned long long p =
            ((unsigned long long)fbits << 32) |
            (unsigned long long)(0xFFFFFFFFu - (unsigned int)si[0]);
        atomicMax(&packed[b], p);
    }
}

__global__ void finalize_kernel(
    int* __restrict__ out,
    const unsigned long long* __restrict__ packed,
    const int* __restrict__ flag, const int* __restrict__ writecol,
    int B, int L)
{
    const int b = blockIdx.x * blockDim.x + threadIdx.x;
    if (b >= B) return;
    if (!flag[b]) return;
    const unsigned long long p = packed[b];
    const int idx = (int)(0xFFFFFFFFu - (unsigned int)(p & 0xFFFFFFFFull));
    out[(size_t)b * (L + 1) + writecol[b]] = idx;
}

extern "C" void kernel_launch(void* const* d_in, const int* in_sizes, int n_in,
                              void* d_out, int out_size, void* d_ws, size_t ws_size,
                              hipStream_t stream) {
    const float* draft_probs   = (const float*)d_in[0];
    const float* target_probs  = (const float*)d_in[1];
    const float* uniform_probs = (const float*)d_in[2];
    const int*   draft_ids     = (const int*)d_in[3];
    const int*   cu            = (const int*)d_in[4];
    const int*   bonus         = (const int*)d_in[5];
    int*         out           = (int*)d_out;

    const int NT = in_sizes[2];
    const int V  = in_sizes[0] / NT;
    const int B  = in_sizes[4];
    const int L  = out_size / B - 1;

    unsigned long long* packed = (unsigned long long*)d_ws;
    int* flag     = (int*)((char*)d_ws + (size_t)B * 8);
    int* recrow   = (int*)((char*)d_ws + (size_t)B * 8 + (size_t)B * 4);
    int* writecol = (int*)((char*)d_ws + (size_t)B * 8 + (size_t)B * 8);

    const int bthreads = 256;
    const int bblocks  = (B + bthreads - 1) / bthreads;

    chain_kernel<<<bblocks, bthreads, 0, stream>>>(
        draft_probs, target_probs, uniform_probs, draft_ids, cu, bonus,
        out, packed, flag, recrow, writecol, B, V, NT, L);

    dim3 grid(B, SPLITS);
    argmax_partial_kernel<<<grid, 256, 0, stream>>>(
        target_probs, nullptr, packed, flag, recrow, V);

    finalize_kernel<<<bblocks, bthreads, 0, stream>>>(
        out, packed, flag, writecol, B, L);
}